// Round 4
// baseline (256.290 us; speedup 1.0000x reference)
//
#include <hip/hip_runtime.h>
#include <cstdint>
#include <cstddef>

#define NP    1024
#define FD    10
#define NV    4
#define BSZ   128
#define NPAIR (BSZ * NV)   // 512
#define NSET  (NPAIR * 2)  // 1024 column sets (goal + state per pair)
#define TPB   256
#define RPT   2            // rows per thread (512 rows per block / 256 threads)

// d_ws layout (21 MB):
//   vis2 : [NSET][NP] float4  (-2 * normalized vis)   @ 0        (16 MB)
//   cs   : [NSET][NP] float   (||vis||^2, unscaled)   @ 16777216 ( 4 MB)
//   part : [2048] float       (per-block raw sums)    @ 20971520
#define OFF_CS   16777216
#define OFF_PART 20971520

// Set id s: pair = s>>1; (s&1)==1 -> state (achieved), ==0 -> goal (desired).
// Main block bid: pd = bid>>1, half = bid&1; columns = set[pd], rows = set[pd^1].
//   pd = pair*2 + d: d=0 -> cols=goal, rows=state (reward_s2g direction)
//                    d=1 -> cols=state, rows=goal (reward_g2s direction)

extern "C" __global__ __launch_bounds__(256)
void chamfer_stage(const float* __restrict__ ag, const float* __restrict__ dg,
                   const float* __restrict__ nmean, const float* __restrict__ nstd,
                   float* __restrict__ vis2o, float* __restrict__ cso)
{
    const int s   = blockIdx.x;                 // set id 0..1023
    const int tid = threadIdx.x;
    const float* src = ((s & 1) ? ag : dg) + (size_t)(s >> 1) * (NP * FD);
    float st[4], mn[4];
#pragma unroll
    for (int j = 0; j < 4; ++j) {
        st[j] = -2.0f * nstd[5 + j];
        mn[j] = -2.0f * nmean[5 + j];
    }
    float4* vout = (float4*)vis2o + (size_t)s * NP;
    float*  cout = cso + (size_t)s * NP;
    for (int n = tid; n < NP; n += 256) {
        const float* p = src + (size_t)n * FD + 5;
        float v0 = fmaf(p[0], st[0], mn[0]);
        float v1 = fmaf(p[1], st[1], mn[1]);
        float v2 = fmaf(p[2], st[2], mn[2]);
        float v3 = fmaf(p[3], st[3], mn[3]);
        vout[n] = make_float4(v0, v1, v2, v3);
        // vis2 = -2*vis -> ||vis||^2 = 0.25 * dot (same op order as round 3)
        cout[n] = 0.25f * (v0 * v0 + v1 * v1 + v2 * v2 + v3 * v3);
    }
}

extern "C" __global__ __launch_bounds__(TPB, 8)
void chamfer_pairs(const float* __restrict__ vis2, const float* __restrict__ cs,
                   const float* __restrict__ ag, const float* __restrict__ dg,
                   const float* __restrict__ nmean, const float* __restrict__ nstd,
                   float* __restrict__ partial /* [2048] */)
{
    __shared__ float redbuf[TPB / 64];

    const int bid  = blockIdx.x;        // 0..2047
    const int pd   = bid >> 1;          // 0..1023: pair*2 + d
    const int half = bid & 1;           // which 512-row half
    const int pair = pd >> 1;
    const int d    = pd & 1;
    const int tid  = threadIdx.x;

    // Column set = set[pd]; row set = set[pd^1]. Column loads below are
    // wave-uniform addresses into a read-only buffer -> scalar s_load path.
    const float4* cvis  = (const float4*)vis2 + (size_t)pd * NP;
    const float*  ccs   = cs + (size_t)pd * NP;
    const float4* rvis4 = (const float4*)vis2 + (size_t)(pd ^ 1) * NP;
    const float*  rcs   = cs + (size_t)(pd ^ 1) * NP;

    // Epilogue xy sources (raw inputs): d=0 rows=state(ag)/cols=goal(dg); d=1 swapped.
    const float* rxyg = ((d == 0) ? ag : dg) + (size_t)pair * (NP * FD);
    const float* cxyg = ((d == 0) ? dg : ag) + (size_t)pair * (NP * FD);

    float4 rv[RPT];
    float  rthr[RPT];    // (rs + bestd') > 6  <=>  bestd' > 6 - rs
    float  bestd[RPT];
    int    bblk[RPT];
#pragma unroll
    for (int r = 0; r < RPT; ++r) {
        int n = half * 512 + tid + TPB * r;
        float4 t = rvis4[n];                     // stored as -2*vis; unscale for row use
        rv[r] = make_float4(-0.5f * t.x, -0.5f * t.y, -0.5f * t.z, -0.5f * t.w);
        rthr[r] = 6.0f - rcs[n];
        bestd[r] = 3.0e38f;
        bblk[r]  = 0;
    }

    for (int m = 0; m < NP; m += 8) {
        // Uniform, invariant loads -> SGPRs (s_load_dwordx16); no LDS, no VALU.
        float4 c0 = cvis[m + 0];
        float4 c1 = cvis[m + 1];
        float4 c2 = cvis[m + 2];
        float4 c3 = cvis[m + 3];
        float4 c4 = cvis[m + 4];
        float4 c5 = cvis[m + 5];
        float4 c6 = cvis[m + 6];
        float4 c7 = cvis[m + 7];
        float4 csA = *(const float4*)(ccs + m);
        float4 csB = *(const float4*)(ccs + m + 4);
#pragma unroll
        for (int r = 0; r < RPT; ++r) {
            float4 v = rv[r];
            float d0 = fmaf(v.x, c0.x, csA.x); d0 = fmaf(v.y, c0.y, d0); d0 = fmaf(v.z, c0.z, d0); d0 = fmaf(v.w, c0.w, d0);
            float d1 = fmaf(v.x, c1.x, csA.y); d1 = fmaf(v.y, c1.y, d1); d1 = fmaf(v.z, c1.z, d1); d1 = fmaf(v.w, c1.w, d1);
            float d2 = fmaf(v.x, c2.x, csA.z); d2 = fmaf(v.y, c2.y, d2); d2 = fmaf(v.z, c2.z, d2); d2 = fmaf(v.w, c2.w, d2);
            float d3 = fmaf(v.x, c3.x, csA.w); d3 = fmaf(v.y, c3.y, d3); d3 = fmaf(v.z, c3.z, d3); d3 = fmaf(v.w, c3.w, d3);
            float d4 = fmaf(v.x, c4.x, csB.x); d4 = fmaf(v.y, c4.y, d4); d4 = fmaf(v.z, c4.z, d4); d4 = fmaf(v.w, c4.w, d4);
            float d5 = fmaf(v.x, c5.x, csB.y); d5 = fmaf(v.y, c5.y, d5); d5 = fmaf(v.z, c5.z, d5); d5 = fmaf(v.w, c5.w, d5);
            float d6 = fmaf(v.x, c6.x, csB.z); d6 = fmaf(v.y, c6.y, d6); d6 = fmaf(v.z, c6.z, d6); d6 = fmaf(v.w, c6.w, d6);
            float d7 = fmaf(v.x, c7.x, csB.w); d7 = fmaf(v.y, c7.y, d7); d7 = fmaf(v.z, c7.z, d7); d7 = fmaf(v.w, c7.w, d7);
            // block-min via v_min3 tree (exact; no NaNs)
            float p0 = fminf(fminf(d0, d1), d2);
            float p1 = fminf(fminf(d3, d4), d5);
            float p2 = fminf(d6, d7);
            float bm = fminf(fminf(p0, p1), p2);
            bool lt = bm < bestd[r];             // strict < keeps FIRST block on ties
            bestd[r] = fminf(bestd[r], bm);
            bblk[r]  = lt ? m : bblk[r];
        }
    }

    // Epilogue: replay the winning block (identical fmaf chain on the same
    // staged values -> bit-exact) to recover the first-tie index, then gather
    // xy from the raw inputs and accumulate the L2 distance.
    const float std0 = nstd[0], mean0 = nmean[0];
    const float std1 = nstd[1], mean1 = nmean[1];
    float sum = 0.0f;
#pragma unroll
    for (int r = 0; r < RPT; ++r) {
        int n  = half * 512 + tid + TPB * r;
        int mb = bblk[r];
        float4 v = rv[r];
        float4 csA = *(const float4*)(ccs + mb);
        float4 csB = *(const float4*)(ccs + mb + 4);
        float cse[8] = {csA.x, csA.y, csA.z, csA.w, csB.x, csB.y, csB.z, csB.w};
        float dd[8];
#pragma unroll
        for (int j = 0; j < 8; ++j) {
            float4 c = cvis[mb + j];             // divergent -> vector gather (L2-hot)
            float t = fmaf(v.x, c.x, cse[j]);
            t = fmaf(v.y, c.y, t);
            t = fmaf(v.z, c.z, t);
            t = fmaf(v.w, c.w, t);
            dd[j] = t;
        }
        int sel = 0;
#pragma unroll
        for (int j = 7; j >= 0; --j)             // descending: smallest j wins ties
            if (dd[j] == bestd[r]) sel = j;
        int idx = mb + sel;

        float gx = fmaf(cxyg[(size_t)idx * FD + 0], std0, mean0);
        float gy = fmaf(cxyg[(size_t)idx * FD + 1], std1, mean1);
        float ax = fmaf(rxyg[(size_t)n * FD + 0], std0, mean0);
        float ay = fmaf(rxyg[(size_t)n * FD + 1], std1, mean1);
        float dx = ax - gx;
        float dy = ay - gy;
        float dist = sqrtf(dx * dx + dy * dy);
        if (bestd[r] > rthr[r]) dist = 1.0f;     // min_d > LATENT_DIST_THRESHOLD
        sum += dist;
    }

    // Wave shuffle reduce, then across the 4 waves.
    for (int o = 32; o > 0; o >>= 1) sum += __shfl_down(sum, o, 64);
    if ((tid & 63) == 0) redbuf[tid >> 6] = sum;
    __syncthreads();
    if (tid == 0) {
        float s = redbuf[0] + redbuf[1] + redbuf[2] + redbuf[3];
        partial[bid] = s;                        // raw positive sum
    }
}

extern "C" __global__ void chamfer_final(const float* __restrict__ partial,
                                         float* __restrict__ out)
{
    int b = threadIdx.x;
    if (b < BSZ) {
        float s = 0.0f;
#pragma unroll
        for (int i = 0; i < 16; ++i) s += partial[b * 16 + i];
        // out = -( sum over 4 views, 2 dirs, 2 halves ) / (1024 * 2 * 4)
        out[b] = s * (-1.0f / 8192.0f);
    }
}

extern "C" void kernel_launch(void* const* d_in, const int* in_sizes, int n_in,
                              void* d_out, int out_size, void* d_ws, size_t ws_size,
                              hipStream_t stream)
{
    const float* ag = (const float*)d_in[0];   // achieved_goal (128,4,1024,10)
    const float* dg = (const float*)d_in[1];   // desired_goal  (128,4,1024,10)
    const float* nm = (const float*)d_in[2];   // norm_mean (10,)
    const float* ns = (const float*)d_in[3];   // norm_std  (10,)

    char*  ws      = (char*)d_ws;
    float* vis2    = (float*)(ws);             // 16 MB
    float* csbuf   = (float*)(ws + OFF_CS);    //  4 MB
    float* partial = (float*)(ws + OFF_PART);  //  8 KB

    chamfer_stage<<<NSET, 256, 0, stream>>>(ag, dg, nm, ns, vis2, csbuf);
    chamfer_pairs<<<NSET * 2, TPB, 0, stream>>>(vis2, csbuf, ag, dg, nm, ns, partial);
    chamfer_final<<<1, BSZ, 0, stream>>>(partial, (float*)d_out);
}